// Round 9
// baseline (184.137 us; speedup 1.0000x reference)
//
#include <hip/hip_runtime.h>
#include <math.h>

// Problem constants
#define BQ 2
#define LQ 2048
#define DQ 1024
#define HQ 16
#define HDQ 64

typedef __bf16 bf16_t;
typedef bf16_t bf16x4 __attribute__((ext_vector_type(4)));
typedef bf16_t bf16x8 __attribute__((ext_vector_type(8)));
typedef _Float16 f16_t;
typedef f16_t f16x4 __attribute__((ext_vector_type(4)));
typedef f16_t f16x8 __attribute__((ext_vector_type(8)));
typedef float f32x4 __attribute__((ext_vector_type(4)));

// async global->LDS, 16B per lane; LDS dest = wave-uniform base + lane*16
__device__ __forceinline__ void gld16(const void* g, void* l) {
    __builtin_amdgcn_global_load_lds(
        (const __attribute__((address_space(1))) void*)g,
        (__attribute__((address_space(3))) void*)l, 16, 0, 0);
}

// ---------------- fused prep: x->bf16, W transposes, packed rope table ------
// grid 8320: [0,4096) convert x | [4096,7168) Wqkv^T | [7168,8192) Wout^T |
// [8192,8320) rope pack rpk[l*16+i] = (cos_i, cos_{16+i}, sin_i, sin_{16+i})
__global__ __launch_bounds__(256) void prep_kernel(
    const float* __restrict__ x, const float* __restrict__ Wqkv,
    const float* __restrict__ Wout, const float* __restrict__ cosT,
    const float* __restrict__ sinT,
    bf16_t* __restrict__ xb, bf16_t* __restrict__ Wqkvt,
    bf16_t* __restrict__ Wot, float4* __restrict__ rpk)
{
    __shared__ float t[32][33];
    const int bid = blockIdx.x, tid = threadIdx.x;
    if (bid < 4096) {
        const int i = (bid * 256 + tid) * 4;
        float4 v = *(const float4*)(x + i);
        bf16x4 o;
        o[0] = (bf16_t)v.x; o[1] = (bf16_t)v.y; o[2] = (bf16_t)v.z; o[3] = (bf16_t)v.w;
        *(bf16x4*)(xb + i) = o;
    } else if (bid < 8192) {
        const bool isq = bid < 7168;
        const int b = isq ? bid - 4096 : bid - 7168;
        const int N = isq ? 3072 : 1024;
        const int gx = isq ? 96 : 32;
        const float* in = isq ? Wqkv : Wout;
        bf16_t* out = isq ? Wqkvt : Wot;
        const int k0 = (b / gx) * 32, n0 = (b % gx) * 32;
        const int r = tid >> 3, c4 = (tid & 7) * 4;
        float4 v = *(const float4*)(in + (size_t)(k0 + r) * N + n0 + c4);
        t[r][c4 + 0] = v.x; t[r][c4 + 1] = v.y;
        t[r][c4 + 2] = v.z; t[r][c4 + 3] = v.w;
        __syncthreads();
        bf16x4 o;
        o[0] = (bf16_t)t[c4 + 0][r]; o[1] = (bf16_t)t[c4 + 1][r];
        o[2] = (bf16_t)t[c4 + 2][r]; o[3] = (bf16_t)t[c4 + 3][r];
        *(bf16x4*)(out + (size_t)(n0 + r) * 1024 + k0 + c4) = o;
    } else {
        const int idx = (bid - 8192) * 256 + tid;   // 0..32767
        const int i = idx & 15, l = idx >> 4;
        rpk[idx] = make_float4(cosT[l * 64 + i], cosT[l * 64 + 16 + i],
                               sinT[l * 64 + i], sinT[l * 64 + 16 + i]);
    }
}

// ---------------- QKV GEMM: 128x128 tile, BK=64, XOR-swizzled LDS ----------
// Fused RoPE epilogue -> q,k bf16 [B,H,L,HD] (Q pre-scaled 0.125*log2e);
// v fp16 [B,H,HD,L].
__global__ __launch_bounds__(256) void qkv_gemm_kernel(
    const bf16_t* __restrict__ A, const bf16_t* __restrict__ Bt,
    bf16_t* __restrict__ qo, bf16_t* __restrict__ ko, f16_t* __restrict__ vo,
    const float4* __restrict__ rpk)
{
    __shared__ __align__(16) bf16_t As[128][64];
    __shared__ __align__(16) bf16_t Bs[128][64];
    const int K = 1024;
    const int tid  = threadIdx.x;
    const int lane = tid & 63;
    const int w    = tid >> 6;
    const int lr   = lane & 15, quad = lane >> 4;
    const int wm   = w & 1, wn = w >> 1;
    const int m0   = blockIdx.y * 128, n0 = blockIdx.x * 128;
    const int srow8 = lane >> 3;
    const int swz   = ((lane & 7) ^ srow8) * 8;

    f32x4 acc[4][4];
#pragma unroll
    for (int i = 0; i < 4; i++)
#pragma unroll
        for (int j = 0; j < 4; j++)
#pragma unroll
            for (int r = 0; r < 4; r++) acc[i][j][r] = 0.f;

    for (int k0 = 0; k0 < K; k0 += 64) {
        __syncthreads();
#pragma unroll
        for (int j = 0; j < 4; j++) {
            const int g = w * 4 + j;
            const int rr = g * 8 + srow8;
            gld16(A  + (size_t)(m0 + rr) * K + k0 + swz, &As[g * 8][0]);
            gld16(Bt + (size_t)(n0 + rr) * K + k0 + swz, &Bs[g * 8][0]);
        }
        __syncthreads();

        bf16x8 af[4][2], bfr[4][2];
#pragma unroll
        for (int t = 0; t < 4; t++)
#pragma unroll
            for (int h = 0; h < 2; h++) {
                const int cA = ((quad + 4 * h) ^ (lr & 7)) * 8;
                af[t][h]  = *(const bf16x8*)(&As[wm * 64 + t * 16 + lr][cA]);
                bfr[t][h] = *(const bf16x8*)(&Bs[wn * 64 + t * 16 + lr][cA]);
            }
#pragma unroll
        for (int h = 0; h < 2; h++)
#pragma unroll
            for (int mt = 0; mt < 4; mt++)
#pragma unroll
                for (int nt = 0; nt < 4; nt++)
                    acc[mt][nt] = __builtin_amdgcn_mfma_f32_16x16x32_bf16(
                        af[mt][h], bfr[nt][h], acc[mt][nt], 0, 0, 0);
    }

    const int which = n0 >> 10;                          // 0=q 1=k 2=v
    const int h = ((n0 & 1023) + wn * 64) >> 6;          // wave-uniform head
    if (which == 2) {
        // V: store transposed fp16 [B,H,HD,L]; r=0..3 consecutive l -> f16x4
#pragma unroll
        for (int mt = 0; mt < 4; mt++) {
            const int m = m0 + wm * 64 + mt * 16 + quad * 4;
            const int b = m >> 11, l = m & 2047;
            f16_t* p = vo + ((size_t)(b * HQ + h) * HDQ) * LQ + l;
#pragma unroll
            for (int nt = 0; nt < 4; nt++) {
                f16x4 pv;
#pragma unroll
                for (int r = 0; r < 4; r++) pv[r] = (f16_t)acc[mt][nt][r];
                *(f16x4*)(p + (size_t)(nt * 16 + lr) * LQ) = pv;
            }
        }
    } else {
        // Q/K: fused RoPE via packed table; Q gets softmax prescale
        bf16_t* dst = which ? ko : qo;
        const float qs = which ? 1.0f : 0.18033688011f;  // 0.125*log2(e)
#pragma unroll
        for (int mt = 0; mt < 4; mt++)
#pragma unroll
            for (int r = 0; r < 4; r++) {
                const int m = m0 + wm * 64 + mt * 16 + quad * 4 + r;
                const int b = m >> 11, l = m & 2047;
                const float4 rp = rpk[l * 16 + lr];
                const float a0 = acc[mt][0][r], a1 = acc[mt][1][r];
                const float a2 = acc[mt][2][r], a3 = acc[mt][3][r];
                bf16_t* p = dst + ((size_t)(b * HQ + h) * LQ + l) * HDQ;
                p[lr]      = (bf16_t)((a0 * rp.x - a2 * rp.z) * qs);
                p[16 + lr] = (bf16_t)((a1 * rp.y - a3 * rp.w) * qs);
                p[32 + lr] = (bf16_t)((a2 * rp.x + a0 * rp.z) * qs);
                p[48 + lr] = (bf16_t)((a3 * rp.y + a1 * rp.w) * qs);
            }
    }
}

// ---------------- Out GEMM: 64x128 tile, BK=64, XOR swizzle -----------------
__global__ __launch_bounds__(256) void out_gemm_kernel(
    const bf16_t* __restrict__ A, const bf16_t* __restrict__ Bt,
    float* __restrict__ fo, const float* __restrict__ bias)
{
    __shared__ __align__(16) bf16_t As[64][64];
    __shared__ __align__(16) bf16_t Bs[128][64];
    const int K = 1024, N = 1024;
    const int tid  = threadIdx.x;
    const int lane = tid & 63;
    const int w    = tid >> 6;
    const int lr   = lane & 15, quad = lane >> 4;
    const int m0   = blockIdx.y * 64, n0 = blockIdx.x * 128;
    const int srow8 = lane >> 3;
    const int swz   = ((lane & 7) ^ srow8) * 8;

    f32x4 acc[4][2];
#pragma unroll
    for (int i = 0; i < 4; i++)
#pragma unroll
        for (int j = 0; j < 2; j++)
#pragma unroll
            for (int r = 0; r < 4; r++) acc[i][j][r] = 0.f;

    for (int k0 = 0; k0 < K; k0 += 64) {
        __syncthreads();
#pragma unroll
        for (int j = 0; j < 2; j++) {
            const int g = w * 2 + j;
            gld16(A + (size_t)(m0 + g * 8 + srow8) * K + k0 + swz, &As[g * 8][0]);
        }
#pragma unroll
        for (int j = 0; j < 4; j++) {
            const int g = w * 4 + j;
            gld16(Bt + (size_t)(n0 + g * 8 + srow8) * K + k0 + swz, &Bs[g * 8][0]);
        }
        __syncthreads();

        bf16x8 af[4][2], bfr[2][2];
#pragma unroll
        for (int h = 0; h < 2; h++) {
            const int cA = ((quad + 4 * h) ^ (lr & 7)) * 8;
#pragma unroll
            for (int t = 0; t < 4; t++)
                af[t][h] = *(const bf16x8*)(&As[t * 16 + lr][cA]);
#pragma unroll
            for (int t = 0; t < 2; t++)
                bfr[t][h] = *(const bf16x8*)(&Bs[w * 32 + t * 16 + lr][cA]);
        }
#pragma unroll
        for (int h = 0; h < 2; h++)
#pragma unroll
            for (int mt = 0; mt < 4; mt++)
#pragma unroll
                for (int nt = 0; nt < 2; nt++)
                    acc[mt][nt] = __builtin_amdgcn_mfma_f32_16x16x32_bf16(
                        af[mt][h], bfr[nt][h], acc[mt][nt], 0, 0, 0);
    }

#pragma unroll
    for (int nt = 0; nt < 2; nt++) {
        const int n = n0 + w * 32 + nt * 16 + lr;
        const float bj = bias[n];
#pragma unroll
        for (int mt = 0; mt < 4; mt++)
#pragma unroll
            for (int r = 0; r < 4; r++) {
                const int m = m0 + mt * 16 + quad * 4 + r;
                fo[(size_t)m * N + n] = acc[mt][nt][r] + bj;
            }
    }
}

// ---------------- bf16/fp16 MFMA flash attention v6 -------------------------
// S^T formulation: QK^T computed as A=K, B=Q (identical fragment maps), so
// C-layout (row=kv=quad*4+r, col=q=lane&15) == A-operand layout of
// mfma_f32_16x16x16_f16. After exp2, P packs to f16x4 A-frags IN REGISTERS —
// no LDS round-trip. PV: 16x16x16_f16 with V fp16 ds_read_b64 B-frags.
// Fixed-reference softmax (Q pre-scaled, exp2 direct). Dbuf, 1 barrier/iter.
__global__ __launch_bounds__(256) void attn_kernel6(
    const bf16_t* __restrict__ qb, const bf16_t* __restrict__ kb,
    const f16_t* __restrict__ vtb, bf16_t* __restrict__ ob)
{
    __shared__ __align__(16) bf16_t Kb[2][64][80];
    __shared__ __align__(16) f16_t  Vs[2][64][72];

    const int tid  = threadIdx.x;
    const int lane = tid & 63;
    const int w    = tid >> 6;
    const int quad = lane >> 4;
    const int lr   = lane & 15;
    const int bh   = blockIdx.x;          // same-head blocks share K/V in L2
    const int qt   = 31 - blockIdx.y;     // heaviest blocks dispatch first

    const bf16_t* Kh = kb  + (size_t)bh * LQ * HDQ;
    const f16_t*  Vh = vtb + (size_t)bh * HDQ * LQ;

    const int r0 = tid >> 3, c0 = (tid & 7) * 8;
    const int r1 = r0 + 32;

    f16x4 ones;
#pragma unroll
    for (int j = 0; j < 4; j++) ones[j] = (f16_t)1.0f;

    const int qrow = qt * 64 + w * 16 + lr;
    const bf16_t* qp = qb + ((size_t)bh * LQ + qrow) * HDQ;
    const bf16x8 qa0 = *(const bf16x8*)(qp + quad * 8);
    const bf16x8 qa1 = *(const bf16x8*)(qp + 32 + quad * 8);

    bf16x8 kp0 = *(const bf16x8*)(Kh + (size_t)r0 * HDQ + c0);
    bf16x8 kp1 = *(const bf16x8*)(Kh + (size_t)r1 * HDQ + c0);
    f16x8  vp0 = *(const f16x8*)(Vh + (size_t)r0 * LQ + c0);
    f16x8  vp1 = *(const f16x8*)(Vh + (size_t)r1 * LQ + c0);

    f32x4 Oacc[4], lacc;
#pragma unroll
    for (int d = 0; d < 4; d++)
#pragma unroll
        for (int r = 0; r < 4; r++) Oacc[d][r] = 0.f;
#pragma unroll
    for (int r = 0; r < 4; r++) lacc[r] = 0.f;

    for (int kt = 0; kt <= qt; kt++) {
        const int buf = kt & 1;
        *(bf16x8*)(&Kb[buf][r0][c0]) = kp0;
        *(bf16x8*)(&Kb[buf][r1][c0]) = kp1;
        *(f16x8*)(&Vs[buf][r0][c0]) = vp0;
        *(f16x8*)(&Vs[buf][r1][c0]) = vp1;
        __syncthreads();
        if (kt < qt) {
            const bf16_t* kn = Kh + (size_t)(kt + 1) * 64 * HDQ;
            kp0 = *(const bf16x8*)(kn + (size_t)r0 * HDQ + c0);
            kp1 = *(const bf16x8*)(kn + (size_t)r1 * HDQ + c0);
            vp0 = *(const f16x8*)(Vh + (size_t)r0 * LQ + (kt + 1) * 64 + c0);
            vp1 = *(const f16x8*)(Vh + (size_t)r1 * LQ + (kt + 1) * 64 + c0);
        }

        // S^T = K Q^T  (row=kv=quad*4+r, col=q=lr), exp2-domain
        f32x4 s[4];
#pragma unroll
        for (int nt = 0; nt < 4; nt++) {
            const bf16x8 kf0 = *(const bf16x8*)(&Kb[buf][nt * 16 + lr][quad * 8]);
            const bf16x8 kf1 = *(const bf16x8*)(&Kb[buf][nt * 16 + lr][32 + quad * 8]);
            f32x4 z = {0.f, 0.f, 0.f, 0.f};
            z = __builtin_amdgcn_mfma_f32_16x16x32_bf16(kf0, qa0, z, 0, 0, 0);
            z = __builtin_amdgcn_mfma_f32_16x16x32_bf16(kf1, qa1, z, 0, 0, 0);
            s[nt] = z;
        }
        // causal mask (diag tile only): kv = nt*16+quad*4+r  vs  q = w*16+lr
        if (kt == qt) {
#pragma unroll
            for (int nt = 0; nt < 4; nt++)
#pragma unroll
                for (int r = 0; r < 4; r++)
                    if (nt * 16 + quad * 4 + r > w * 16 + lr) s[nt][r] = -INFINITY;
        }
        // p = exp2(s); pack into A-frags (f16) — no LDS round-trip
        f16x4 pa[4];
#pragma unroll
        for (int nt = 0; nt < 4; nt++)
#pragma unroll
            for (int r = 0; r < 4; r++)
                pa[nt][r] = (f16_t)__builtin_amdgcn_exp2f(s[nt][r]);

        // O += P V (16x16x16 f16), l += row-sum(P)
#pragma unroll
        for (int d = 0; d < 4; d++)
#pragma unroll
            for (int nt = 0; nt < 4; nt++) {
                const f16x4 vf = *(const f16x4*)(&Vs[buf][d * 16 + lr][nt * 16 + quad * 4]);
                Oacc[d] = __builtin_amdgcn_mfma_f32_16x16x16f16(pa[nt], vf, Oacc[d], 0, 0, 0);
            }
#pragma unroll
        for (int nt = 0; nt < 4; nt++)
            lacc = __builtin_amdgcn_mfma_f32_16x16x16f16(pa[nt], ones, lacc, 0, 0, 0);
    }

    // epilogue: O / l -> ob [B, L, H*HD] bf16  (row=q=quad*4+r, col=d=lr)
    const int b = bh >> 4, h = bh & 15;
#pragma unroll
    for (int r = 0; r < 4; r++) {
        const float inv = 1.0f / lacc[r];
        const int q = qt * 64 + w * 16 + quad * 4 + r;
        bf16_t* op = ob + ((size_t)(b * LQ + q)) * 1024 + h * 64;
#pragma unroll
        for (int d = 0; d < 4; d++)
            op[d * 16 + lr] = (bf16_t)(Oacc[d][r] * inv);
    }
}

// ---------------- launch -----------------------------------------------------
extern "C" void kernel_launch(void* const* d_in, const int* in_sizes, int n_in,
                              void* d_out, int out_size, void* d_ws, size_t ws_size,
                              hipStream_t stream) {
    const float* x        = (const float*)d_in[0];
    const float* rope_cos = (const float*)d_in[1];
    const float* rope_sin = (const float*)d_in[2];
    const float* W_qkv    = (const float*)d_in[3];
    const float* W_out    = (const float*)d_in[4];
    const float* b_out    = (const float*)d_in[5];
    float* out = (float*)d_out;

    // ws (bytes): xb 8M | qb 8M | kb 8M | vth 8M | ob 8M | Wqkvt 6M | Wot 2M | rpk 0.5M
    char* wsb = (char*)d_ws;
    bf16_t* xb    = (bf16_t*)(wsb);
    bf16_t* qbf   = (bf16_t*)(wsb + ((size_t)8  << 20));
    bf16_t* kbf   = (bf16_t*)(wsb + ((size_t)16 << 20));
    f16_t*  vth   = (f16_t*) (wsb + ((size_t)24 << 20));
    bf16_t* ob    = (bf16_t*)(wsb + ((size_t)32 << 20));
    bf16_t* Wqkvt = (bf16_t*)(wsb + ((size_t)40 << 20));
    bf16_t* Wot   = (bf16_t*)(wsb + ((size_t)46 << 20));
    float4* rpk   = (float4*)(wsb + ((size_t)48 << 20));

    prep_kernel<<<8320, 256, 0, stream>>>(x, W_qkv, W_out, rope_cos, rope_sin,
                                          xb, Wqkvt, Wot, rpk);

    dim3 g1(3072 / 128, 4096 / 128);
    qkv_gemm_kernel<<<g1, 256, 0, stream>>>(xb, Wqkvt, qbf, kbf, vth, rpk);

    dim3 g2(32, 32);   // x = bh (L2 locality), y -> qt = 31-y (heavy first)
    attn_kernel6<<<g2, 256, 0, stream>>>(qbf, kbf, vth, ob);

    dim3 g3(1024 / 128, 4096 / 64);
    out_gemm_kernel<<<g3, 256, 0, stream>>>(ob, Wot, out, b_out);
}

// Round 10
// 175.477 us; speedup vs baseline: 1.0494x; 1.0494x over previous
//
#include <hip/hip_runtime.h>
#include <math.h>

// Problem constants
#define BQ 2
#define LQ 2048
#define DQ 1024
#define HQ 16
#define HDQ 64

typedef __bf16 bf16_t;
typedef bf16_t bf16x4 __attribute__((ext_vector_type(4)));
typedef bf16_t bf16x8 __attribute__((ext_vector_type(8)));
typedef _Float16 f16_t;
typedef f16_t f16x4 __attribute__((ext_vector_type(4)));
typedef f16_t f16x8 __attribute__((ext_vector_type(8)));
typedef float f32x4 __attribute__((ext_vector_type(4)));

// ---------------- fused prep: x->bf16, W transposes, packed rope table ------
// grid 8320: [0,4096) convert x | [4096,7168) Wqkv^T | [7168,8192) Wout^T |
// [8192,8320) rope pack rpk[l*16+i] = (cos_i, cos_{16+i}, sin_i, sin_{16+i})
__global__ __launch_bounds__(256) void prep_kernel(
    const float* __restrict__ x, const float* __restrict__ Wqkv,
    const float* __restrict__ Wout, const float* __restrict__ cosT,
    const float* __restrict__ sinT,
    bf16_t* __restrict__ xb, bf16_t* __restrict__ Wqkvt,
    bf16_t* __restrict__ Wot, float4* __restrict__ rpk)
{
    __shared__ float t[32][33];
    const int bid = blockIdx.x, tid = threadIdx.x;
    if (bid < 4096) {
        const int i = (bid * 256 + tid) * 4;
        float4 v = *(const float4*)(x + i);
        bf16x4 o;
        o[0] = (bf16_t)v.x; o[1] = (bf16_t)v.y; o[2] = (bf16_t)v.z; o[3] = (bf16_t)v.w;
        *(bf16x4*)(xb + i) = o;
    } else if (bid < 8192) {
        const bool isq = bid < 7168;
        const int b = isq ? bid - 4096 : bid - 7168;
        const int N = isq ? 3072 : 1024;
        const int gx = isq ? 96 : 32;
        const float* in = isq ? Wqkv : Wout;
        bf16_t* out = isq ? Wqkvt : Wot;
        const int k0 = (b / gx) * 32, n0 = (b % gx) * 32;
        const int r = tid >> 3, c4 = (tid & 7) * 4;
        float4 v = *(const float4*)(in + (size_t)(k0 + r) * N + n0 + c4);
        t[r][c4 + 0] = v.x; t[r][c4 + 1] = v.y;
        t[r][c4 + 2] = v.z; t[r][c4 + 3] = v.w;
        __syncthreads();
        bf16x4 o;
        o[0] = (bf16_t)t[c4 + 0][r]; o[1] = (bf16_t)t[c4 + 1][r];
        o[2] = (bf16_t)t[c4 + 2][r]; o[3] = (bf16_t)t[c4 + 3][r];
        *(bf16x4*)(out + (size_t)(n0 + r) * 1024 + k0 + c4) = o;
    } else {
        const int idx = (bid - 8192) * 256 + tid;   // 0..32767
        const int i = idx & 15, l = idx >> 4;
        rpk[idx] = make_float4(cosT[l * 64 + i], cosT[l * 64 + 16 + i],
                               sinT[l * 64 + i], sinT[l * 64 + 16 + i]);
    }
}

// ---------------- QKV GEMM: 128x128, BK=64, reg-prefetch pipeline -----------
// Staging via global->reg loads (in flight across the whole compute phase)
// committed with ds_write_b128 — barriers drain only lgkmcnt, never vmcnt.
// XOR-swizzled LDS: LDS[row][c] = global[row][c ^ (row&7)]; frag reads XOR
// back -> conflict-free (verified 0 conflicts R8). Fused RoPE epilogue.
__global__ __launch_bounds__(256) void qkv_gemm_kernel(
    const bf16_t* __restrict__ A, const bf16_t* __restrict__ Bt,
    bf16_t* __restrict__ qo, bf16_t* __restrict__ ko, f16_t* __restrict__ vo,
    const float4* __restrict__ rpk)
{
    __shared__ __align__(16) bf16_t As[128][64];
    __shared__ __align__(16) bf16_t Bs[128][64];
    const int K = 1024;
    const int tid  = threadIdx.x;
    const int lane = tid & 63;
    const int w    = tid >> 6;
    const int lr   = lane & 15, quad = lane >> 4;
    const int wm   = w & 1, wn = w >> 1;
    const int m0   = blockIdx.y * 128, n0 = blockIdx.x * 128;
    const int srow8 = lane >> 3;                 // row within 8-row group
    const int swz   = ((lane & 7) ^ srow8) * 8;  // swizzled global k-chunk
    const int wc    = (lane & 7) * 8;            // LDS chunk (lane-contiguous)

    f32x4 acc[4][4];
#pragma unroll
    for (int i = 0; i < 4; i++)
#pragma unroll
        for (int j = 0; j < 4; j++)
#pragma unroll
            for (int r = 0; r < 4; r++) acc[i][j][r] = 0.f;

    // prefetch tile 0 into registers
    bf16x8 ar[4], br[4];
#pragma unroll
    for (int j = 0; j < 4; j++) {
        const int rr = (w * 4 + j) * 8 + srow8;
        ar[j] = *(const bf16x8*)(A  + (size_t)(m0 + rr) * K + swz);
        br[j] = *(const bf16x8*)(Bt + (size_t)(n0 + rr) * K + swz);
    }

    for (int k0 = 0; k0 < K; k0 += 64) {
        __syncthreads();             // prior compute's LDS reads done
#pragma unroll
        for (int j = 0; j < 4; j++) {
            const int rg = (w * 4 + j) * 8 + srow8;
            *(bf16x8*)(&As[rg][wc]) = ar[j];
            *(bf16x8*)(&Bs[rg][wc]) = br[j];
        }
        __syncthreads();             // drains lgkmcnt only (no pending VMEM)
        if (k0 + 64 < K) {           // issue next tile's loads; they fly
#pragma unroll                       // across the whole compute phase below
            for (int j = 0; j < 4; j++) {
                const int rr = (w * 4 + j) * 8 + srow8;
                ar[j] = *(const bf16x8*)(A  + (size_t)(m0 + rr) * K + k0 + 64 + swz);
                br[j] = *(const bf16x8*)(Bt + (size_t)(n0 + rr) * K + k0 + 64 + swz);
            }
        }

        bf16x8 af[4][2], bfr[4][2];
#pragma unroll
        for (int t = 0; t < 4; t++)
#pragma unroll
            for (int h = 0; h < 2; h++) {
                const int cA = ((quad + 4 * h) ^ (lr & 7)) * 8;
                af[t][h]  = *(const bf16x8*)(&As[wm * 64 + t * 16 + lr][cA]);
                bfr[t][h] = *(const bf16x8*)(&Bs[wn * 64 + t * 16 + lr][cA]);
            }
#pragma unroll
        for (int h = 0; h < 2; h++)
#pragma unroll
            for (int mt = 0; mt < 4; mt++)
#pragma unroll
                for (int nt = 0; nt < 4; nt++)
                    acc[mt][nt] = __builtin_amdgcn_mfma_f32_16x16x32_bf16(
                        af[mt][h], bfr[nt][h], acc[mt][nt], 0, 0, 0);
    }

    const int which = n0 >> 10;                          // 0=q 1=k 2=v
    const int h = ((n0 & 1023) + wn * 64) >> 6;          // wave-uniform head
    if (which == 2) {
        // V: store transposed fp16 [B,H,HD,L]; r=0..3 consecutive l -> f16x4
#pragma unroll
        for (int mt = 0; mt < 4; mt++) {
            const int m = m0 + wm * 64 + mt * 16 + quad * 4;
            const int b = m >> 11, l = m & 2047;
            f16_t* p = vo + ((size_t)(b * HQ + h) * HDQ) * LQ + l;
#pragma unroll
            for (int nt = 0; nt < 4; nt++) {
                f16x4 pv;
#pragma unroll
                for (int r = 0; r < 4; r++) pv[r] = (f16_t)acc[mt][nt][r];
                *(f16x4*)(p + (size_t)(nt * 16 + lr) * LQ) = pv;
            }
        }
    } else {
        // Q/K: fused RoPE via packed table; Q gets softmax prescale
        bf16_t* dst = which ? ko : qo;
        const float qs = which ? 1.0f : 0.18033688011f;  // 0.125*log2(e)
#pragma unroll
        for (int mt = 0; mt < 4; mt++)
#pragma unroll
            for (int r = 0; r < 4; r++) {
                const int m = m0 + wm * 64 + mt * 16 + quad * 4 + r;
                const int b = m >> 11, l = m & 2047;
                const float4 rp = rpk[l * 16 + lr];
                const float a0 = acc[mt][0][r], a1 = acc[mt][1][r];
                const float a2 = acc[mt][2][r], a3 = acc[mt][3][r];
                bf16_t* p = dst + ((size_t)(b * HQ + h) * LQ + l) * HDQ;
                p[lr]      = (bf16_t)((a0 * rp.x - a2 * rp.z) * qs);
                p[16 + lr] = (bf16_t)((a1 * rp.y - a3 * rp.w) * qs);
                p[32 + lr] = (bf16_t)((a2 * rp.x + a0 * rp.z) * qs);
                p[48 + lr] = (bf16_t)((a3 * rp.y + a1 * rp.w) * qs);
            }
    }
}

// ---------------- Out GEMM: 64x128, BK=64, reg-prefetch pipeline ------------
__global__ __launch_bounds__(256) void out_gemm_kernel(
    const bf16_t* __restrict__ A, const bf16_t* __restrict__ Bt,
    float* __restrict__ fo, const float* __restrict__ bias)
{
    __shared__ __align__(16) bf16_t As[64][64];
    __shared__ __align__(16) bf16_t Bs[128][64];
    const int K = 1024, N = 1024;
    const int tid  = threadIdx.x;
    const int lane = tid & 63;
    const int w    = tid >> 6;
    const int lr   = lane & 15, quad = lane >> 4;
    const int m0   = blockIdx.y * 64, n0 = blockIdx.x * 128;
    const int srow8 = lane >> 3;
    const int swz   = ((lane & 7) ^ srow8) * 8;
    const int wc    = (lane & 7) * 8;

    f32x4 acc[4][2];
#pragma unroll
    for (int i = 0; i < 4; i++)
#pragma unroll
        for (int j = 0; j < 2; j++)
#pragma unroll
            for (int r = 0; r < 4; r++) acc[i][j][r] = 0.f;

    bf16x8 ar[2], br[4];
#pragma unroll
    for (int j = 0; j < 2; j++)
        ar[j] = *(const bf16x8*)(A + (size_t)(m0 + (w * 2 + j) * 8 + srow8) * K + swz);
#pragma unroll
    for (int j = 0; j < 4; j++)
        br[j] = *(const bf16x8*)(Bt + (size_t)(n0 + (w * 4 + j) * 8 + srow8) * K + swz);

    for (int k0 = 0; k0 < K; k0 += 64) {
        __syncthreads();
#pragma unroll
        for (int j = 0; j < 2; j++)
            *(bf16x8*)(&As[(w * 2 + j) * 8 + srow8][wc]) = ar[j];
#pragma unroll
        for (int j = 0; j < 4; j++)
            *(bf16x8*)(&Bs[(w * 4 + j) * 8 + srow8][wc]) = br[j];
        __syncthreads();
        if (k0 + 64 < K) {
#pragma unroll
            for (int j = 0; j < 2; j++)
                ar[j] = *(const bf16x8*)(A + (size_t)(m0 + (w * 2 + j) * 8 + srow8) * K
                                          + k0 + 64 + swz);
#pragma unroll
            for (int j = 0; j < 4; j++)
                br[j] = *(const bf16x8*)(Bt + (size_t)(n0 + (w * 4 + j) * 8 + srow8) * K
                                          + k0 + 64 + swz);
        }

        bf16x8 af[4][2], bfr[2][2];
#pragma unroll
        for (int h = 0; h < 2; h++) {
            const int cA = ((quad + 4 * h) ^ (lr & 7)) * 8;
#pragma unroll
            for (int t = 0; t < 4; t++)
                af[t][h] = *(const bf16x8*)(&As[t * 16 + lr][cA]);
#pragma unroll
            for (int t = 0; t < 2; t++)
                bfr[t][h] = *(const bf16x8*)(&Bs[w * 32 + t * 16 + lr][cA]);
        }
#pragma unroll
        for (int h = 0; h < 2; h++)
#pragma unroll
            for (int mt = 0; mt < 4; mt++)
#pragma unroll
                for (int nt = 0; nt < 2; nt++)
                    acc[mt][nt] = __builtin_amdgcn_mfma_f32_16x16x32_bf16(
                        af[mt][h], bfr[nt][h], acc[mt][nt], 0, 0, 0);
    }

#pragma unroll
    for (int nt = 0; nt < 2; nt++) {
        const int n = n0 + w * 32 + nt * 16 + lr;
        const float bj = bias[n];
#pragma unroll
        for (int mt = 0; mt < 4; mt++)
#pragma unroll
            for (int r = 0; r < 4; r++) {
                const int m = m0 + mt * 16 + quad * 4 + r;
                fo[(size_t)m * N + n] = acc[mt][nt][r] + bj;
            }
    }
}

// ---------------- bf16/fp16 MFMA flash attention v6 -------------------------
// S^T formulation: A=K, B=Q -> C row=kv, col=q == A-layout of 16x16x16_f16;
// P packs to f16 A-frags in registers (no LDS round-trip). Fixed-reference
// exp2 softmax (Q pre-scaled). Dbuf staging, 1 barrier/iter.
__global__ __launch_bounds__(256) void attn_kernel6(
    const bf16_t* __restrict__ qb, const bf16_t* __restrict__ kb,
    const f16_t* __restrict__ vtb, bf16_t* __restrict__ ob)
{
    __shared__ __align__(16) bf16_t Kb[2][64][80];
    __shared__ __align__(16) f16_t  Vs[2][64][72];

    const int tid  = threadIdx.x;
    const int lane = tid & 63;
    const int w    = tid >> 6;
    const int quad = lane >> 4;
    const int lr   = lane & 15;
    const int bh   = blockIdx.x;
    const int qt   = 31 - blockIdx.y;

    const bf16_t* Kh = kb  + (size_t)bh * LQ * HDQ;
    const f16_t*  Vh = vtb + (size_t)bh * HDQ * LQ;

    const int r0 = tid >> 3, c0 = (tid & 7) * 8;
    const int r1 = r0 + 32;

    f16x4 ones;
#pragma unroll
    for (int j = 0; j < 4; j++) ones[j] = (f16_t)1.0f;

    const int qrow = qt * 64 + w * 16 + lr;
    const bf16_t* qp = qb + ((size_t)bh * LQ + qrow) * HDQ;
    const bf16x8 qa0 = *(const bf16x8*)(qp + quad * 8);
    const bf16x8 qa1 = *(const bf16x8*)(qp + 32 + quad * 8);

    bf16x8 kp0 = *(const bf16x8*)(Kh + (size_t)r0 * HDQ + c0);
    bf16x8 kp1 = *(const bf16x8*)(Kh + (size_t)r1 * HDQ + c0);
    f16x8  vp0 = *(const f16x8*)(Vh + (size_t)r0 * LQ + c0);
    f16x8  vp1 = *(const f16x8*)(Vh + (size_t)r1 * LQ + c0);

    f32x4 Oacc[4], lacc;
#pragma unroll
    for (int d = 0; d < 4; d++)
#pragma unroll
        for (int r = 0; r < 4; r++) Oacc[d][r] = 0.f;
#pragma unroll
    for (int r = 0; r < 4; r++) lacc[r] = 0.f;

    for (int kt = 0; kt <= qt; kt++) {
        const int buf = kt & 1;
        *(bf16x8*)(&Kb[buf][r0][c0]) = kp0;
        *(bf16x8*)(&Kb[buf][r1][c0]) = kp1;
        *(f16x8*)(&Vs[buf][r0][c0]) = vp0;
        *(f16x8*)(&Vs[buf][r1][c0]) = vp1;
        __syncthreads();
        if (kt < qt) {
            const bf16_t* kn = Kh + (size_t)(kt + 1) * 64 * HDQ;
            kp0 = *(const bf16x8*)(kn + (size_t)r0 * HDQ + c0);
            kp1 = *(const bf16x8*)(kn + (size_t)r1 * HDQ + c0);
            vp0 = *(const f16x8*)(Vh + (size_t)r0 * LQ + (kt + 1) * 64 + c0);
            vp1 = *(const f16x8*)(Vh + (size_t)r1 * LQ + (kt + 1) * 64 + c0);
        }

        // S^T = K Q^T  (row=kv=quad*4+r, col=q=lr), exp2-domain
        f32x4 s[4];
#pragma unroll
        for (int nt = 0; nt < 4; nt++) {
            const bf16x8 kf0 = *(const bf16x8*)(&Kb[buf][nt * 16 + lr][quad * 8]);
            const bf16x8 kf1 = *(const bf16x8*)(&Kb[buf][nt * 16 + lr][32 + quad * 8]);
            f32x4 z = {0.f, 0.f, 0.f, 0.f};
            z = __builtin_amdgcn_mfma_f32_16x16x32_bf16(kf0, qa0, z, 0, 0, 0);
            z = __builtin_amdgcn_mfma_f32_16x16x32_bf16(kf1, qa1, z, 0, 0, 0);
            s[nt] = z;
        }
        if (kt == qt) {
#pragma unroll
            for (int nt = 0; nt < 4; nt++)
#pragma unroll
                for (int r = 0; r < 4; r++)
                    if (nt * 16 + quad * 4 + r > w * 16 + lr) s[nt][r] = -INFINITY;
        }
        f16x4 pa[4];
#pragma unroll
        for (int nt = 0; nt < 4; nt++)
#pragma unroll
            for (int r = 0; r < 4; r++)
                pa[nt][r] = (f16_t)__builtin_amdgcn_exp2f(s[nt][r]);

        // O += P V (16x16x16 f16), l += row-sum(P)
#pragma unroll
        for (int d = 0; d < 4; d++)
#pragma unroll
            for (int nt = 0; nt < 4; nt++) {
                const f16x4 vf = *(const f16x4*)(&Vs[buf][d * 16 + lr][nt * 16 + quad * 4]);
                Oacc[d] = __builtin_amdgcn_mfma_f32_16x16x16f16(pa[nt], vf, Oacc[d], 0, 0, 0);
            }
#pragma unroll
        for (int nt = 0; nt < 4; nt++)
            lacc = __builtin_amdgcn_mfma_f32_16x16x16f16(pa[nt], ones, lacc, 0, 0, 0);
    }

    // epilogue: O / l -> ob [B, L, H*HD] bf16  (row=q=quad*4+r, col=d=lr)
    const int b = bh >> 4, h = bh & 15;
#pragma unroll
    for (int r = 0; r < 4; r++) {
        const float inv = 1.0f / lacc[r];
        const int q = qt * 64 + w * 16 + quad * 4 + r;
        bf16_t* op = ob + ((size_t)(b * LQ + q)) * 1024 + h * 64;
#pragma unroll
        for (int d = 0; d < 4; d++)
            op[d * 16 + lr] = (bf16_t)(Oacc[d][r] * inv);
    }
}

// ---------------- launch -----------------------------------------------------
extern "C" void kernel_launch(void* const* d_in, const int* in_sizes, int n_in,
                              void* d_out, int out_size, void* d_ws, size_t ws_size,
                              hipStream_t stream) {
    const float* x        = (const float*)d_in[0];
    const float* rope_cos = (const float*)d_in[1];
    const float* rope_sin = (const float*)d_in[2];
    const float* W_qkv    = (const float*)d_in[3];
    const float* W_out    = (const float*)d_in[4];
    const float* b_out    = (const float*)d_in[5];
    float* out = (float*)d_out;

    // ws (bytes): xb 8M | qb 8M | kb 8M | vth 8M | ob 8M | Wqkvt 6M | Wot 2M | rpk 0.5M
    char* wsb = (char*)d_ws;
    bf16_t* xb    = (bf16_t*)(wsb);
    bf16_t* qbf   = (bf16_t*)(wsb + ((size_t)8  << 20));
    bf16_t* kbf   = (bf16_t*)(wsb + ((size_t)16 << 20));
    f16_t*  vth   = (f16_t*) (wsb + ((size_t)24 << 20));
    bf16_t* ob    = (bf16_t*)(wsb + ((size_t)32 << 20));
    bf16_t* Wqkvt = (bf16_t*)(wsb + ((size_t)40 << 20));
    bf16_t* Wot   = (bf16_t*)(wsb + ((size_t)46 << 20));
    float4* rpk   = (float4*)(wsb + ((size_t)48 << 20));

    prep_kernel<<<8320, 256, 0, stream>>>(x, W_qkv, W_out, rope_cos, rope_sin,
                                          xb, Wqkvt, Wot, rpk);

    dim3 g1(3072 / 128, 4096 / 128);
    qkv_gemm_kernel<<<g1, 256, 0, stream>>>(xb, Wqkvt, qbf, kbf, vth, rpk);

    dim3 g2(32, 32);   // x = bh (L2 locality), y -> qt = 31-y (heavy first)
    attn_kernel6<<<g2, 256, 0, stream>>>(qbf, kbf, vth, ob);

    dim3 g3(1024 / 128, 4096 / 64);
    out_gemm_kernel<<<g3, 256, 0, stream>>>(ob, Wot, out, b_out);
}